// Round 3
// baseline (7821.628 us; speedup 1.0000x reference)
//
#include <hip/hip_runtime.h>

#define B_ 64
#define T_ 512
#define D_ 1024
#define H_ 1024

typedef _Float16 half8 __attribute__((ext_vector_type(8)));
typedef float floatx16 __attribute__((ext_vector_type(16)));

__device__ __forceinline__ float sigm(float x)   { return 1.f / (1.f + __expf(-x)); }
__device__ __forceinline__ float tanh_f(float x) { return 1.f - 2.f / (1.f + __expf(2.f * x)); }

// ---------------- prep: inputs fp32 -> f16 (8 elems / thread) ----------------
__global__ void k_prep_x(const float* __restrict__ x, _Float16* __restrict__ xf) {
  int i = blockIdx.x * blockDim.x + threadIdx.x;   // 0 .. 4194303
  const float4* p = (const float4*)x + (size_t)i * 2;
  float4 a = p[0], b = p[1];
  half8 v;
  v[0]=(_Float16)a.x; v[1]=(_Float16)a.y; v[2]=(_Float16)a.z; v[3]=(_Float16)a.w;
  v[4]=(_Float16)b.x; v[5]=(_Float16)b.y; v[6]=(_Float16)b.z; v[7]=(_Float16)b.w;
  ((half8*)xf)[i] = v;
}

// ---------------- prep: h_{-1} = init_h (f16), zero flags ----------------
__global__ void k_prep_misc(const float* __restrict__ init_h,
                            _Float16* __restrict__ hb1, int* __restrict__ flags) {
  int i = blockIdx.x * blockDim.x + threadIdx.x;   // grid 256x256 = 65536
  hb1[i] = (_Float16)init_h[i];
  if (i < 4096) flags[i] = 0;
}

// =====================================================================
// k_lstm2: two-phase persistent kernel.
//   Phase A (no cross-WG sync): each WG computes xz = x@Wi + b for ITS OWN
//     32 batches x 32 z-cols, all 512 steps; packed 4xf16/thread/step.
//   Phase B (recurrence): per step only the h@Wh contraction (K=1024) is on
//     the serial path; xz read is one 8-B WG-private load, prefetched.
// Sync protocol (proven in R2): write-through agent h-stores -> syncthreads
// (vmcnt drain) -> flag store; consumers poll 128 same-bh flags -> acquire
// fence (buffer_inv, no writeback) -> plain vectorized h loads (L2-merged).
// =====================================================================
template <bool XF16>
__launch_bounds__(256, 1)
__global__ void k_lstm2(const float* __restrict__ x32, const _Float16* __restrict__ xf,
                        const int* __restrict__ lengths, const float* __restrict__ init_c,
                        const float* __restrict__ Wi, const float* __restrict__ Wh,
                        const float* __restrict__ bias,
                        _Float16* __restrict__ hb0, _Float16* __restrict__ hb1,
                        int* __restrict__ flags, unsigned long long* __restrict__ xz,
                        float* __restrict__ out, float* __restrict__ finc,
                        float* __restrict__ finh)
{
  __shared__ _Float16 slab[32768];   // 64 KB: one 1024-K weight slice, B-frag order
  __shared__ float red[4][32][40];   // 20 KB: wave partials, stride 40 conflict-free

  const int w    = blockIdx.x;
  const int bh   = w >> 7;
  const int jc   = w & 127;
  const int t    = threadIdx.x;
  const int wave = t >> 6;
  const int lane = t & 63;
  const int m    = lane & 31;
  const int kh   = lane >> 5;

  const int gate = m >> 3;
  const int col  = gate * H_ + jc * 8 + (m & 7);   // z-column this lane's B-frag covers

  // ---- gather Wi slab (f16, fragment order: slab[kb*512 + lane*8]) ----
  for (int kbb = 0; kbb < 16; ++kbb) {
    const int kb = kbb * 4 + wave;
    const int kc = kb * 16 + kh * 8;
    half8 v;
    #pragma unroll
    for (int j = 0; j < 8; ++j)
      v[j] = (_Float16)Wi[(size_t)(kc + j) * 4096 + col];
    *(half8*)&slab[kb * 512 + lane * 8] = v;
  }

  const int bl = t >> 3, jj = t & 7;
  const int bG = bh * 32 + bl;
  const int jG = jc * 8 + jj;
  const float bz0 = bias[0 * H_ + jG];
  const float bz1 = bias[1 * H_ + jG];
  const float bz2 = bias[2 * H_ + jG];
  const float bz3 = bias[3 * H_ + jG];

  const int bA = bh * 32 + m;                      // A-fragment row (batch)
  const _Float16* xbase   = XF16 ? (xf + (size_t)bA * T_ * D_ + kh * 8) : (const _Float16*)0;
  const float*    xbase32 = x32 + (size_t)bA * T_ * D_ + kh * 8;

  unsigned long long* xzslot = xz + ((size_t)w << 17);   // 512 steps x 256 threads

  __syncthreads();

  // =================== Phase A: x-projection (throughput GEMM) ===================
  for (int s = 0; s < T_; ++s) {
    floatx16 C;
    #pragma unroll
    for (int r = 0; r < 16; ++r) C[r] = 0.f;

    if (XF16) {
      const _Float16* xs = xbase + (size_t)s * D_;
      #pragma unroll
      for (int i = 0; i < 16; ++i) {
        const half8 a  = *(const half8*)(xs + (wave * 16 + i) * 16);
        const half8 bf = *(const half8*)&slab[(wave * 16 + i) * 512 + lane * 8];
        C = __builtin_amdgcn_mfma_f32_32x32x16_f16(a, bf, C, 0, 0, 0);
      }
    } else {
      const float* xs = xbase32 + (size_t)s * D_;
      #pragma unroll
      for (int i = 0; i < 16; ++i) {
        const float4* p = (const float4*)(xs + (wave * 16 + i) * 16);
        float4 u0 = p[0], u1 = p[1];
        half8 a;
        a[0]=(_Float16)u0.x; a[1]=(_Float16)u0.y; a[2]=(_Float16)u0.z; a[3]=(_Float16)u0.w;
        a[4]=(_Float16)u1.x; a[5]=(_Float16)u1.y; a[6]=(_Float16)u1.z; a[7]=(_Float16)u1.w;
        const half8 bf = *(const half8*)&slab[(wave * 16 + i) * 512 + lane * 8];
        C = __builtin_amdgcn_mfma_f32_32x32x16_f16(a, bf, C, 0, 0, 0);
      }
    }

    #pragma unroll
    for (int r = 0; r < 16; ++r) {
      const int row = (r & 3) + 8 * (r >> 2) + 4 * kh;
      red[wave][row][m] = C[r];
    }
    __syncthreads();

    const float z0 = red[0][bl][jj]      + red[1][bl][jj]      + red[2][bl][jj]      + red[3][bl][jj]      + bz0;
    const float z1 = red[0][bl][8 + jj]  + red[1][bl][8 + jj]  + red[2][bl][8 + jj]  + red[3][bl][8 + jj]  + bz1;
    const float z2 = red[0][bl][16 + jj] + red[1][bl][16 + jj] + red[2][bl][16 + jj] + red[3][bl][16 + jj] + bz2;
    const float z3 = red[0][bl][24 + jj] + red[1][bl][24 + jj] + red[2][bl][24 + jj] + red[3][bl][24 + jj] + bz3;

    union { _Float16 h[4]; unsigned long long q; } pk;
    pk.h[0] = (_Float16)z0; pk.h[1] = (_Float16)z1;
    pk.h[2] = (_Float16)z2; pk.h[3] = (_Float16)z3;
    xzslot[s * 256 + t] = pk.q;
    __syncthreads();   // red reuse hazard across iterations
  }

  // ---- swap slab to Wh ----
  for (int kbb = 0; kbb < 16; ++kbb) {
    const int kb = kbb * 4 + wave;
    const int kc = kb * 16 + kh * 8;
    half8 v;
    #pragma unroll
    for (int j = 0; j < 8; ++j)
      v[j] = (_Float16)Wh[(size_t)(kc + j) * 4096 + col];
    *(half8*)&slab[kb * 512 + lane * 8] = v;
  }

  float c = init_c[bG * H_ + jG];
  const int len = lengths[bG];

  int* myflag_w = flags + (w << 4);                        // 64-B padded flags
  int* myflag_p = flags + ((bh * 128 + (t & 127)) << 4);   // same-bh producers

  __syncthreads();

  // =================== Phase B: recurrence ===================
  for (int s = 0; s < T_; ++s) {
    // prefetch my xz (WG-private, 8 B) before the poll
    const unsigned long long q = xzslot[s * 256 + t];

    if (t < 128) {
      int spin = 0;
      while (__hip_atomic_load(myflag_p, __ATOMIC_RELAXED, __HIP_MEMORY_SCOPE_AGENT) < s) {
        __builtin_amdgcn_s_sleep(1);
        if (++spin > (1 << 22)) break;   // safety valve
      }
    }
    __syncthreads();
    __builtin_amdgcn_fence(__ATOMIC_ACQUIRE, "agent");   // buffer_inv (no writeback)

    // h-phase: plain vectorized loads (L2-merged), 2 independent MFMA chains
    const _Float16* hsrc = (s & 1) ? hb0 : hb1;
    const _Float16* hrow = hsrc + (size_t)bA * H_ + kh * 8;
    floatx16 C0, C1;
    #pragma unroll
    for (int r = 0; r < 16; ++r) { C0[r] = 0.f; C1[r] = 0.f; }
    #pragma unroll
    for (int i = 0; i < 8; ++i) {
      const half8 av = *(const half8*)(hrow + (wave * 16 + i) * 16);
      const half8 bf = *(const half8*)&slab[(wave * 16 + i) * 512 + lane * 8];
      C0 = __builtin_amdgcn_mfma_f32_32x32x16_f16(av, bf, C0, 0, 0, 0);
    }
    #pragma unroll
    for (int i = 8; i < 16; ++i) {
      const half8 av = *(const half8*)(hrow + (wave * 16 + i) * 16);
      const half8 bf = *(const half8*)&slab[(wave * 16 + i) * 512 + lane * 8];
      C1 = __builtin_amdgcn_mfma_f32_32x32x16_f16(av, bf, C1, 0, 0, 0);
    }

    #pragma unroll
    for (int r = 0; r < 16; ++r) {
      const int row = (r & 3) + 8 * (r >> 2) + 4 * kh;
      red[wave][row][m] = C0[r] + C1[r];
    }
    __syncthreads();

    union { _Float16 h[4]; unsigned long long q; } upk;
    upk.q = q;
    const float z0 = red[0][bl][jj]      + red[1][bl][jj]      + red[2][bl][jj]      + red[3][bl][jj]      + (float)upk.h[0];
    const float z1 = red[0][bl][8 + jj]  + red[1][bl][8 + jj]  + red[2][bl][8 + jj]  + red[3][bl][8 + jj]  + (float)upk.h[1];
    const float z2 = red[0][bl][16 + jj] + red[1][bl][16 + jj] + red[2][bl][16 + jj] + red[3][bl][16 + jj] + (float)upk.h[2];
    const float z3 = red[0][bl][24 + jj] + red[1][bl][24 + jj] + red[2][bl][24 + jj] + red[3][bl][24 + jj] + (float)upk.h[3];

    const float ig = sigm(z0);
    const float fg = sigm(z1);
    const float gg = tanh_f(z2);
    const float og = sigm(z3);
    c = fg * c + ig * gg;
    const float hv = og * tanh_f(c);

    // publish h_s first (write-through to LLC, packed f16x2)
    {
      const float hv_other = __shfl_xor(hv, 1);
      if (!(t & 1)) {
        union { _Float16 h2[2]; unsigned u; } pk;
        pk.h2[0] = (_Float16)hv;
        pk.h2[1] = (_Float16)hv_other;
        _Float16* hdst = (s & 1) ? hb1 : hb0;
        __hip_atomic_store((unsigned*)(hdst + (size_t)bG * H_ + jG), pk.u,
                           __ATOMIC_RELAXED, __HIP_MEMORY_SCOPE_AGENT);
      }
    }

    out[((size_t)bG * T_ + s) * H_ + jG] = hv;
    if (s == len - 1) { finc[bG * H_ + jG] = c; finh[bG * H_ + jG] = hv; }

    __syncthreads();   // drains vmcnt(0): h stores LLC-acked before flag
    if (t == 0)
      __hip_atomic_store(myflag_w, s + 1, __ATOMIC_RELAXED, __HIP_MEMORY_SCOPE_AGENT);
  }
}

// =====================================================================
// k_lstm (R2 fallback, fused x-phase in-loop) — used when ws too small for xz
// =====================================================================
template <bool XF16>
__launch_bounds__(256, 1)
__global__ void k_lstm(const float* __restrict__ x32, const _Float16* __restrict__ xf,
                       const int* __restrict__ lengths, const float* __restrict__ init_c,
                       const float* __restrict__ Wi, const float* __restrict__ Wh,
                       const float* __restrict__ bias,
                       _Float16* __restrict__ hb0, _Float16* __restrict__ hb1,
                       int* __restrict__ flags,
                       float* __restrict__ out, float* __restrict__ finc,
                       float* __restrict__ finh)
{
  __shared__ _Float16 slab[65536];
  __shared__ float red[4][32][40];

  const int w    = blockIdx.x;
  const int bh   = w >> 7;
  const int jc   = w & 127;
  const int t    = threadIdx.x;
  const int wave = t >> 6;
  const int lane = t & 63;
  const int m    = lane & 31;
  const int kh   = lane >> 5;

  {
    const int gate = m >> 3;
    const int col  = gate * H_ + jc * 8 + (m & 7);
    for (int kbb = 0; kbb < 32; ++kbb) {
      const int kb = kbb * 4 + wave;
      const int kc = kb * 16 + kh * 8;
      half8 v;
      #pragma unroll
      for (int j = 0; j < 8; ++j) {
        const int k = kc + j;
        const float f = (k < D_) ? Wi[(size_t)k * 4096 + col]
                                 : Wh[(size_t)(k - D_) * 4096 + col];
        v[j] = (_Float16)f;
      }
      *(half8*)&slab[kb * 512 + lane * 8] = v;
    }
  }

  const int bl = t >> 3, jj = t & 7;
  const int bG = bh * 32 + bl;
  const int jG = jc * 8 + jj;
  float c = init_c[bG * H_ + jG];
  const int len = lengths[bG];
  const float bz0 = bias[0 * H_ + jG];
  const float bz1 = bias[1 * H_ + jG];
  const float bz2 = bias[2 * H_ + jG];
  const float bz3 = bias[3 * H_ + jG];

  const int bA = bh * 32 + m;
  const _Float16* xbase   = XF16 ? (xf + (size_t)bA * T_ * D_ + kh * 8) : (const _Float16*)0;
  const float*    xbase32 = x32 + (size_t)bA * T_ * D_ + kh * 8;

  int* myflag_w = flags + (w << 4);
  int* myflag_p = flags + ((bh * 128 + (t & 127)) << 4);

  __syncthreads();

  for (int s = 0; s < T_; ++s) {
    floatx16 C;
    #pragma unroll
    for (int r = 0; r < 16; ++r) C[r] = 0.f;

    half8 a[16];
    if (XF16) {
      const _Float16* xs = xbase + (size_t)s * D_;
      #pragma unroll
      for (int i = 0; i < 16; ++i)
        a[i] = *(const half8*)(xs + (wave * 16 + i) * 16);
    } else {
      const float* xs = xbase32 + (size_t)s * D_;
      #pragma unroll
      for (int i = 0; i < 16; ++i) {
        const float4* p = (const float4*)(xs + (wave * 16 + i) * 16);
        float4 u0 = p[0], u1 = p[1];
        half8 v;
        v[0]=(_Float16)u0.x; v[1]=(_Float16)u0.y; v[2]=(_Float16)u0.z; v[3]=(_Float16)u0.w;
        v[4]=(_Float16)u1.x; v[5]=(_Float16)u1.y; v[6]=(_Float16)u1.z; v[7]=(_Float16)u1.w;
        a[i] = v;
      }
    }
    #pragma unroll
    for (int i = 0; i < 16; ++i) {
      const half8 bf = *(const half8*)&slab[(wave * 16 + i) * 512 + lane * 8];
      C = __builtin_amdgcn_mfma_f32_32x32x16_f16(a[i], bf, C, 0, 0, 0);
    }

    if (t < 128) {
      int spin = 0;
      while (__hip_atomic_load(myflag_p, __ATOMIC_RELAXED, __HIP_MEMORY_SCOPE_AGENT) < s) {
        __builtin_amdgcn_s_sleep(1);
        if (++spin > (1 << 22)) break;
      }
    }
    __syncthreads();
    __builtin_amdgcn_fence(__ATOMIC_ACQUIRE, "agent");

    const _Float16* hsrc = (s & 1) ? hb0 : hb1;
    const _Float16* hrow = hsrc + (size_t)bA * H_ + kh * 8;
    #pragma unroll
    for (int i = 0; i < 16; ++i) {
      const half8 av = *(const half8*)(hrow + (wave * 16 + i) * 16);
      const half8 bf = *(const half8*)&slab[(64 + wave * 16 + i) * 512 + lane * 8];
      C = __builtin_amdgcn_mfma_f32_32x32x16_f16(av, bf, C, 0, 0, 0);
    }

    #pragma unroll
    for (int r = 0; r < 16; ++r) {
      const int row = (r & 3) + 8 * (r >> 2) + 4 * kh;
      red[wave][row][m] = C[r];
    }
    __syncthreads();

    const float z0 = red[0][bl][jj]      + red[1][bl][jj]      + red[2][bl][jj]      + red[3][bl][jj]      + bz0;
    const float z1 = red[0][bl][8 + jj]  + red[1][bl][8 + jj]  + red[2][bl][8 + jj]  + red[3][bl][8 + jj]  + bz1;
    const float z2 = red[0][bl][16 + jj] + red[1][bl][16 + jj] + red[2][bl][16 + jj] + red[3][bl][16 + jj] + bz2;
    const float z3 = red[0][bl][24 + jj] + red[1][bl][24 + jj] + red[2][bl][24 + jj] + red[3][bl][24 + jj] + bz3;

    const float ig = sigm(z0);
    const float fg = sigm(z1);
    const float gg = tanh_f(z2);
    const float og = sigm(z3);
    c = fg * c + ig * gg;
    const float hv = og * tanh_f(c);

    {
      const float hv_other = __shfl_xor(hv, 1);
      if (!(t & 1)) {
        union { _Float16 h2[2]; unsigned u; } pk;
        pk.h2[0] = (_Float16)hv;
        pk.h2[1] = (_Float16)hv_other;
        _Float16* hdst = (s & 1) ? hb1 : hb0;
        __hip_atomic_store((unsigned*)(hdst + (size_t)bG * H_ + jG), pk.u,
                           __ATOMIC_RELAXED, __HIP_MEMORY_SCOPE_AGENT);
      }
    }

    out[((size_t)bG * T_ + s) * H_ + jG] = hv;
    if (s == len - 1) { finc[bG * H_ + jG] = c; finh[bG * H_ + jG] = hv; }

    __syncthreads();
    if (t == 0)
      __hip_atomic_store(myflag_w, s + 1, __ATOMIC_RELAXED, __HIP_MEMORY_SCOPE_AGENT);
  }
}

// ---------------- host ----------------
extern "C" void kernel_launch(void* const* d_in, const int* in_sizes, int n_in,
                              void* d_out, int out_size, void* d_ws, size_t ws_size,
                              hipStream_t stream) {
  const float* x32    = (const float*)d_in[0];
  const int*   lens   = (const int*)  d_in[1];
  const float* init_c = (const float*)d_in[2];
  const float* init_h = (const float*)d_in[3];
  const float* Wi     = (const float*)d_in[4];
  const float* Wh     = (const float*)d_in[5];
  const float* bias   = (const float*)d_in[6];

  float* out   = (float*)d_out;
  float* fin_c = out + (size_t)B_ * T_ * H_;
  float* fin_h = fin_c + (size_t)B_ * H_;

  char* ws = (char*)d_ws;
  int*                flags = (int*)ws;                          // 16 KB
  _Float16*           hb0   = (_Float16*)(ws + 16384);           // 128 KB
  _Float16*           hb1   = hb0 + (size_t)B_ * H_;             // 128 KB
  unsigned long long* xz    = (unsigned long long*)(ws + (1ull << 20));   // 256 MB
  _Float16*           xf16  = (_Float16*)(ws + (257ull << 20));  // 64 MB
  _Float16*           xf16s = (_Float16*)(ws + (1ull << 20));    // small-ws location

  const size_t need2_f16 = 321ull << 20;   // xz + xf16
  const size_t need2_f32 = 257ull << 20;   // xz only (phase A reads f32 x)
  const size_t need1_f16 = 65ull << 20;    // R2 path

  k_prep_misc<<<256, 256, 0, stream>>>(init_h, hb1, flags);
  if (ws_size >= need2_f16) {
    k_prep_x<<<16384, 256, 0, stream>>>(x32, xf16);
    k_lstm2<true><<<256, 256, 0, stream>>>(x32, xf16, lens, init_c, Wi, Wh, bias,
                                           hb0, hb1, flags, xz, out, fin_c, fin_h);
  } else if (ws_size >= need2_f32) {
    k_lstm2<false><<<256, 256, 0, stream>>>(x32, (const _Float16*)0, lens, init_c, Wi, Wh, bias,
                                            hb0, hb1, flags, xz, out, fin_c, fin_h);
  } else if (ws_size >= need1_f16) {
    k_prep_x<<<16384, 256, 0, stream>>>(x32, xf16s);
    k_lstm<true><<<256, 256, 0, stream>>>(x32, xf16s, lens, init_c, Wi, Wh, bias,
                                          hb0, hb1, flags, out, fin_c, fin_h);
  } else {
    k_lstm<false><<<256, 256, 0, stream>>>(x32, (const _Float16*)0, lens, init_c, Wi, Wh, bias,
                                           hb0, hb1, flags, out, fin_c, fin_h);
  }
}